// Round 11
// baseline (221.878 us; speedup 1.0000x reference)
//
#include <hip/hip_runtime.h>

// GCN 2-layer. R11: pair-decomposed, LDS-staged aggregation (zero divergent
// global requests in agg passes).
//  k_sort  : bucket sort by dst>>7, atomic reservation (at request-law floor)
//  k_sort2 : per-bucket chunk sub-sort via LDS double buffer (coalesced
//            write-back), fused deg -> dinv/u, emits chunkOff[nbuck][nch+1]
//  k_agg1  : grid = nch*25 pairs (src-chunk c, 32-bucket dst-window g):
//            stage u-slice 16KB in LDS -> per-edge LDS read + LDS atomic ->
//            partials P1[c][node] (all coalesced)
//  k_mid   : reduce P1 + MLP -> w
//  k_agg2  : same with 16-bucket windows, SoA float2 slices -> P2
//  k_out   : reduce P2 + log_softmax + mean + last-block finalize
// packed word: bits[16:0]=src, bits[23:17]=dst&127.
// Session laws: divergent request ~8.5-9.5 cyc/CU regardless of occupancy/
// batching/nt/L1-windowing (R2-R10). Staging must bound grid x slice traffic
// (R5/R8) and must be LDS, not L1 (R9). SoA in LDS (R8 conflicts).

#define TPB 512
#define TPB2 256
#define SORT_BLK 256
#define BSHIFT 7
#define BNODES 128
#define MAXBUCK 1024
#define BSTRIDE 6144
#define CSHIFT 12
#define CSZ 4096
#define MAXCH 32
#define GB1 32           // buckets per window, agg1 (4096 dst nodes)
#define GB2 16           // buckets per window, agg2 (2048 dst nodes)

// ---------------- bucket sort (count+place fused, atomic reservation) --------

__global__ __launch_bounds__(TPB) void k_sort(const int* __restrict__ ei, int E, int epb,
                                              int nbuck, int* __restrict__ gcur,
                                              unsigned* __restrict__ packed) {
    __shared__ int h[MAXBUCK];
    for (int b = threadIdx.x; b < nbuck; b += TPB) h[b] = 0;
    __syncthreads();
    const int4* d4 = (const int4*)(ei + E);
    int nq = epb >> 2;
    int q0 = blockIdx.x * nq;
    for (int j = threadIdx.x; j < nq; j += TPB) {
        int q = q0 + j;
        int e = q << 2;
        if (e + 3 < E) {
            int4 v = d4[q];
            atomicAdd(&h[v.x >> BSHIFT], 1);
            atomicAdd(&h[v.y >> BSHIFT], 1);
            atomicAdd(&h[v.z >> BSHIFT], 1);
            atomicAdd(&h[v.w >> BSHIFT], 1);
        } else {
            for (int k = 0; k < 4; ++k)
                if (e + k < E) atomicAdd(&h[(ei + E)[e + k] >> BSHIFT], 1);
        }
    }
    __syncthreads();
    for (int b = threadIdx.x; b < nbuck; b += TPB) {
        int c = h[b];
        h[b] = c ? atomicAdd(&gcur[b], c) : 0;
    }
    __syncthreads();
    const int4* s4 = (const int4*)ei;
    for (int j = threadIdx.x; j < nq; j += TPB) {
        int q = q0 + j;
        int e = q << 2;
        if (e + 3 < E) {
            int4 vs = s4[q];
            int4 vd = d4[q];
            int b, p;
            b = vd.x >> BSHIFT; p = atomicAdd(&h[b], 1);
            packed[b * BSTRIDE + p] = ((unsigned)(vd.x & (BNODES - 1)) << 17) | (unsigned)vs.x;
            b = vd.y >> BSHIFT; p = atomicAdd(&h[b], 1);
            packed[b * BSTRIDE + p] = ((unsigned)(vd.y & (BNODES - 1)) << 17) | (unsigned)vs.y;
            b = vd.z >> BSHIFT; p = atomicAdd(&h[b], 1);
            packed[b * BSTRIDE + p] = ((unsigned)(vd.z & (BNODES - 1)) << 17) | (unsigned)vs.z;
            b = vd.w >> BSHIFT; p = atomicAdd(&h[b], 1);
            packed[b * BSTRIDE + p] = ((unsigned)(vd.w & (BNODES - 1)) << 17) | (unsigned)vs.w;
        } else {
            for (int k = 0; k < 4; ++k) {
                int ee = e + k;
                if (ee < E) {
                    int s = ei[ee], d = ei[E + ee];
                    int b = d >> BSHIFT;
                    int p = atomicAdd(&h[b], 1);
                    packed[b * BSTRIDE + p] = ((unsigned)(d & (BNODES - 1)) << 17) | (unsigned)s;
                }
            }
        }
    }
}

// ---- per-bucket chunk sub-sort (LDS dbuf, coalesced writeback) + deg/u ------

__global__ __launch_bounds__(TPB2) void k_sort2(unsigned* __restrict__ packed,
                                                const int* __restrict__ gcur,
                                                const float* __restrict__ x,
                                                float* __restrict__ dinv,
                                                float* __restrict__ u,
                                                int* __restrict__ chunkOff,
                                                int nch, int N) {
    __shared__ unsigned wbuf[BSTRIDE];
    __shared__ unsigned wbuf2[BSTRIDE];
    __shared__ int cntc[4][MAXCH];
    __shared__ int cntd[4][BNODES];
    __shared__ int scanA[MAXCH + 1];
    __shared__ int cur[MAXCH];
    int tid = threadIdx.x;
    int wv = tid >> 6;
    for (int k = tid; k < 4 * MAXCH; k += TPB2) ((int*)cntc)[k] = 0;
    for (int k = tid; k < 4 * BNODES; k += TPB2) ((int*)cntd)[k] = 0;
    __syncthreads();
    int b = blockIdx.x;
    int sz = min(gcur[b], BSTRIDE);
    unsigned* gbase = packed + (size_t)b * BSTRIDE;
    for (int j = tid; j < sz; j += TPB2) {
        unsigned wd = gbase[j];
        wbuf[j] = wd;
        atomicAdd(&cntc[wv][(wd & 0x1FFFF) >> CSHIFT], 1);
        atomicAdd(&cntd[wv][(wd >> 17) & 127], 1);
    }
    __syncthreads();
    if (tid < BNODES) {
        int node = (b << BSHIFT) + tid;
        if (node < N) {
            int deg = cntd[0][tid] + cntd[1][tid] + cntd[2][tid] + cntd[3][tid];
            float di = rsqrtf((float)(deg + 1));   // +1 self-loop
            dinv[node] = di;
            u[node] = di * x[node];
        }
    }
    if (tid == 0) {
        int run = 0;
        for (int c = 0; c < nch; ++c) {
            int v = cntc[0][c] + cntc[1][c] + cntc[2][c] + cntc[3][c];
            scanA[c] = run;
            run += v;
        }
        scanA[nch] = run;
    }
    __syncthreads();
    if (tid <= nch) chunkOff[b * (MAXCH + 1) + tid] = scanA[tid];
    if (tid < nch) cur[tid] = scanA[tid];
    __syncthreads();
    // scatter into LDS (cheap), then write back coalesced
    for (int j = tid; j < sz; j += TPB2) {
        unsigned wd = wbuf[j];
        int c = (wd & 0x1FFFF) >> CSHIFT;
        int p = atomicAdd(&cur[c], 1);
        wbuf2[p] = wd;
    }
    __syncthreads();
    for (int j = tid; j < sz; j += TPB2) gbase[j] = wbuf2[j];
}

// -------- layer-1 aggregation: (chunk, 32-bucket window) pairs, LDS slice ----

__global__ __launch_bounds__(TPB) void k_agg1(const unsigned* __restrict__ packed,
                                              const int* __restrict__ chunkOff,
                                              const float* __restrict__ u,
                                              float* __restrict__ P1,
                                              int nbuck, int G, int N) {
    __shared__ float stage[CSZ];            // 16 KB u-slice
    __shared__ float acc[GB1 * BNODES];     // 16 KB window accumulator
    int tid = threadIdx.x;
    int c = blockIdx.x / G, g = blockIdx.x % G;
    int gb = c << CSHIFT;
    // stage slice (coalesced float4)
    #pragma unroll
    for (int it = 0; it < CSZ / TPB / 4; ++it) {
        int k = it * TPB * 4 + tid * 4;
        int idx = gb + k;
        if (idx + 3 < N) {
            *(float4*)(stage + k) = *(const float4*)(u + idx);
        } else {
            #pragma unroll
            for (int e = 0; e < 4; ++e)
                stage[k + e] = (idx + e < N) ? u[idx + e] : 0.f;
        }
    }
    for (int k = tid; k < GB1 * BNODES; k += TPB) acc[k] = 0.f;
    __syncthreads();
    int wv = tid >> 6, lane = tid & 63;
    int nwin = min(GB1, nbuck - (g << 5));
    for (int lb = wv; lb < nwin; lb += TPB / 64) {
        int b = (g << 5) + lb;
        const int* off = chunkOff + b * (MAXCH + 1);
        int o0 = off[c], o1 = off[c + 1];
        const unsigned* gbase = packed + (size_t)b * BSTRIDE;
        for (int j = o0 + lane; j < o1; j += 64) {
            unsigned wd = gbase[j];
            atomicAdd(&acc[(lb << 7) | ((wd >> 17) & 127)], stage[wd & (CSZ - 1)]);
        }
    }
    __syncthreads();
    int nodeBase = g << 12;
    for (int t = tid; t < GB1 * BNODES; t += TPB) {
        int node = nodeBase + t;
        if (node < N) P1[(size_t)c * N + node] = acc[t];
    }
}

// ---------------- reduce P1 + MLP -> w ----------------

__global__ __launch_bounds__(TPB) void k_mid(const float* __restrict__ P1,
                                             const float* __restrict__ dinv,
                                             const float* __restrict__ u,
                                             const float* __restrict__ W1,
                                             const float* __restrict__ b1,
                                             const float* __restrict__ W2,
                                             float2* __restrict__ w, int nch, int N) {
    __shared__ float sW1[64], sb1[64], sW2[128];
    int tid = threadIdx.x;
    if (tid < 64) { sW1[tid] = W1[tid]; sb1[tid] = b1[tid]; }
    else if (tid < 192) sW2[tid - 64] = W2[tid - 64];
    __syncthreads();
    int i = blockIdx.x * TPB + tid;
    if (i < N) {
        float s = 0.f;
        for (int c = 0; c < nch; ++c) s += P1[(size_t)c * N + i];
        float di = dinv[i];
        float sv = di * (s + u[i]);            // self-loop term dinv*u
        float z0 = 0.f, z1 = 0.f;
        #pragma unroll
        for (int j = 0; j < 64; ++j) {
            float h = fmaxf(fmaf(sv, sW1[j], sb1[j]), 0.f);
            z0 = fmaf(h, sW2[2 * j], z0);
            z1 = fmaf(h, sW2[2 * j + 1], z1);
        }
        w[i] = make_float2(di * z0, di * z1);  // pre-scaled by dinv[src]
    }
}

// -------- layer-2 aggregation: (chunk, 16-bucket window) pairs, SoA ----------

__global__ __launch_bounds__(TPB) void k_agg2(const unsigned* __restrict__ packed,
                                              const int* __restrict__ chunkOff,
                                              const float2* __restrict__ w,
                                              float2* __restrict__ P2,
                                              int nbuck, int G, int N) {
    __shared__ float sx[CSZ], sy[CSZ];            // 32 KB slice (SoA)
    __shared__ float accx[GB2 * BNODES], accy[GB2 * BNODES];   // 16 KB
    int tid = threadIdx.x;
    int c = blockIdx.x / G, g = blockIdx.x % G;
    int gb = c << CSHIFT;
    #pragma unroll
    for (int it = 0; it < CSZ / TPB / 2; ++it) {   // 2 float2 per thread per it
        int k = it * TPB * 2 + tid * 2;
        int idx = gb + k;
        if (idx + 1 < N) {
            float4 v = *(const float4*)((const float*)(w + idx));
            sx[k] = v.x; sy[k] = v.y;
            sx[k + 1] = v.z; sy[k + 1] = v.w;
        } else {
            float2 a = (idx < N) ? w[idx] : make_float2(0.f, 0.f);
            float2 bb = (idx + 1 < N) ? w[idx + 1] : make_float2(0.f, 0.f);
            sx[k] = a.x; sy[k] = a.y;
            sx[k + 1] = bb.x; sy[k + 1] = bb.y;
        }
    }
    for (int k = tid; k < GB2 * BNODES; k += TPB) { accx[k] = 0.f; accy[k] = 0.f; }
    __syncthreads();
    int wv = tid >> 6, lane = tid & 63;
    int nwin = min(GB2, nbuck - (g << 4));
    for (int lb = wv; lb < nwin; lb += TPB / 64) {
        int b = (g << 4) + lb;
        const int* off = chunkOff + b * (MAXCH + 1);
        int o0 = off[c], o1 = off[c + 1];
        const unsigned* gbase = packed + (size_t)b * BSTRIDE;
        for (int j = o0 + lane; j < o1; j += 64) {
            unsigned wd = gbase[j];
            int sidx = wd & (CSZ - 1);
            int bin = (lb << 7) | ((wd >> 17) & 127);
            atomicAdd(&accx[bin], sx[sidx]);
            atomicAdd(&accy[bin], sy[sidx]);
        }
    }
    __syncthreads();
    int nodeBase = g << 11;
    for (int t = tid; t < GB2 * BNODES; t += TPB) {
        int node = nodeBase + t;
        if (node < N) P2[(size_t)c * N + node] = make_float2(accx[t], accy[t]);
    }
}

// -------- reduce P2 + log_softmax + mean + last-block finalize ---------------

__global__ __launch_bounds__(TPB) void k_out(const float2* __restrict__ P2,
                                             const float* __restrict__ dinv,
                                             const float2* __restrict__ w,
                                             const float* __restrict__ b2,
                                             float* __restrict__ accum,
                                             int* __restrict__ done,
                                             float* __restrict__ out,
                                             float invN, int nch, int N) {
    int tid = threadIdx.x;
    int i = blockIdx.x * TPB + tid;
    float l0 = 0.f, l1 = 0.f;
    if (i < N) {
        float sxv = 0.f, syv = 0.f;
        for (int c = 0; c < nch; ++c) {
            float2 v = P2[(size_t)c * N + i];
            sxv += v.x; syv += v.y;
        }
        float di = dinv[i];
        float2 wi = w[i];
        float a0 = di * (sxv + wi.x) + b2[0];
        float a1 = di * (syv + wi.y) + b2[1];
        float m = fmaxf(a0, a1);
        float lse = m + logf(expf(a0 - m) + expf(a1 - m));
        l0 = a0 - lse;
        l1 = a1 - lse;
    }
    #pragma unroll
    for (int off = 32; off > 0; off >>= 1) {
        l0 += __shfl_down(l0, off, 64);
        l1 += __shfl_down(l1, off, 64);
    }
    __shared__ float s0[TPB / 64], s1[TPB / 64];
    int wid = tid >> 6, lane = tid & 63;
    if (lane == 0) { s0[wid] = l0; s1[wid] = l1; }
    __syncthreads();
    if (tid == 0) {
        float t0 = 0.f, t1 = 0.f;
        #pragma unroll
        for (int k = 0; k < TPB / 64; ++k) { t0 += s0[k]; t1 += s1[k]; }
        atomicAdd(&accum[0], t0);
        atomicAdd(&accum[1], t1);
        __threadfence();
        int prev = atomicAdd(done, 1);
        if (prev == (int)gridDim.x - 1) {
            float a0 = atomicAdd(&accum[0], 0.0f);
            float a1 = atomicAdd(&accum[1], 0.0f);
            out[0] = a0 * invN;
            out[1] = a1 * invN;
        }
    }
}

__global__ void k_finalize(const float* __restrict__ accum, float* __restrict__ out, float invN) {
    out[0] = accum[0] * invN;
    out[1] = accum[1] * invN;
}

// ---------------- fallback (global-atomic path) ----------------

#define FTPB 256
__global__ void k_hist(const int* __restrict__ dst, int E, int* __restrict__ deg) {
    int e = blockIdx.x * FTPB + threadIdx.x;
    if (e < E) atomicAdd(&deg[dst[e]], 1);
}
__global__ void k_dinv_u(const int* __restrict__ deg, const float* __restrict__ x,
                         float* __restrict__ dinv, float* __restrict__ u, int N) {
    int i = blockIdx.x * FTPB + threadIdx.x;
    if (i < N) {
        float di = rsqrtf((float)(deg[i] + 1));
        dinv[i] = di;
        u[i] = di * x[i];
    }
}
__global__ void k_scatter1(const int* __restrict__ ei, int E,
                           const float* __restrict__ u, float* __restrict__ t) {
    int e = blockIdx.x * FTPB + threadIdx.x;
    if (e < E) atomicAdd(&t[ei[E + e]], u[ei[e]]);
}
__global__ void k_node_mid_fb(const float* __restrict__ dinv, const float* __restrict__ u,
                              const float* __restrict__ t,
                              const float* __restrict__ W1, const float* __restrict__ b1,
                              const float* __restrict__ W2, float2* __restrict__ w, int N) {
    __shared__ float sW1[64], sb1[64], sW2[128];
    if (threadIdx.x < 64) { sW1[threadIdx.x] = W1[threadIdx.x]; sb1[threadIdx.x] = b1[threadIdx.x]; }
    if (threadIdx.x < 128) sW2[threadIdx.x] = W2[threadIdx.x];
    __syncthreads();
    int i = blockIdx.x * FTPB + threadIdx.x;
    if (i < N) {
        float di = dinv[i];
        float s = di * (t[i] + u[i]);
        float z0 = 0.f, z1 = 0.f;
        #pragma unroll
        for (int j = 0; j < 64; ++j) {
            float h = fmaxf(fmaf(s, sW1[j], sb1[j]), 0.f);
            z0 = fmaf(h, sW2[2 * j], z0);
            z1 = fmaf(h, sW2[2 * j + 1], z1);
        }
        w[i] = make_float2(di * z0, di * z1);
    }
}
__global__ void k_scatter2(const int* __restrict__ ei, int E,
                           const float2* __restrict__ w, float* __restrict__ acc) {
    int e = blockIdx.x * FTPB + threadIdx.x;
    if (e < E) {
        float2 ws = w[ei[e]];
        int d = ei[E + e];
        atomicAdd(&acc[2 * d], ws.x);
        atomicAdd(&acc[2 * d + 1], ws.y);
    }
}
__global__ void k_node_out_fb(const float* __restrict__ dinv, const float2* __restrict__ w,
                              const float2* __restrict__ acc, const float* __restrict__ b2,
                              float* __restrict__ accum, int N) {
    int i = blockIdx.x * FTPB + threadIdx.x;
    float l0 = 0.f, l1 = 0.f;
    if (i < N) {
        float di = dinv[i];
        float2 a = acc[i];
        float2 ww = w[i];
        float a0 = di * (a.x + ww.x) + b2[0];
        float a1 = di * (a.y + ww.y) + b2[1];
        float m = fmaxf(a0, a1);
        float lse = m + logf(expf(a0 - m) + expf(a1 - m));
        l0 = a0 - lse;
        l1 = a1 - lse;
    }
    #pragma unroll
    for (int off = 32; off > 0; off >>= 1) {
        l0 += __shfl_down(l0, off, 64);
        l1 += __shfl_down(l1, off, 64);
    }
    __shared__ float s0[FTPB / 64], s1[FTPB / 64];
    int wid = threadIdx.x >> 6, lane = threadIdx.x & 63;
    if (lane == 0) { s0[wid] = l0; s1[wid] = l1; }
    __syncthreads();
    if (threadIdx.x == 0) {
        float t0 = 0.f, t1 = 0.f;
        #pragma unroll
        for (int k = 0; k < FTPB / 64; ++k) { t0 += s0[k]; t1 += s1[k]; }
        atomicAdd(&accum[0], t0);
        atomicAdd(&accum[1], t1);
    }
}

static inline size_t align16(size_t v) { return (v + 15) & ~(size_t)15; }

extern "C" void kernel_launch(void* const* d_in, const int* in_sizes, int n_in,
                              void* d_out, int out_size, void* d_ws, size_t ws_size,
                              hipStream_t stream) {
    const float* x  = (const float*)d_in[0];
    const int*   ei = (const int*)d_in[1];
    const float* W1 = (const float*)d_in[2];
    const float* b1 = (const float*)d_in[3];
    const float* W2 = (const float*)d_in[4];
    const float* b2 = (const float*)d_in[5];
    float* out = (float*)d_out;

    const int N = in_sizes[0];
    const int E = in_sizes[1] / 2;
    const int nbuck = (N + BNODES - 1) >> BSHIFT;
    const int nch = (N + CSZ - 1) >> CSHIFT;
    const int G1 = (nbuck + GB1 - 1) / GB1;
    const int G2 = (nbuck + GB2 - 1) / GB2;
    const int gridN = (N + FTPB - 1) / FTPB;
    const int gridE = (E + FTPB - 1) / FTPB;

    size_t offPacked = 0;
    size_t offW      = align16(offPacked + (size_t)nbuck * BSTRIDE * 4);
    size_t offDinv   = align16(offW + (size_t)N * 8);
    size_t offU      = align16(offDinv + (size_t)N * 4);
    size_t offGcur   = align16(offU + (size_t)N * 4);
    size_t offAccum  = offGcur + (size_t)nbuck * 4;    // memset'd with gcur
    size_t offDone   = offAccum + 8;
    size_t offCOff   = align16(offDone + 4);
    size_t offP1     = align16(offCOff + (size_t)nbuck * (MAXCH + 1) * 4);
    size_t offP2     = align16(offP1 + (size_t)nch * N * 4);
    size_t need      = offP2 + (size_t)nch * N * 8;

    if (ws_size >= need && nbuck <= MAXBUCK && N < (1 << 17) && nch <= MAXCH) {
        unsigned* packed   = (unsigned*)((char*)d_ws + offPacked);
        float2*   w        = (float2*)((char*)d_ws + offW);
        float*    dinv     = (float*)((char*)d_ws + offDinv);
        float*    u        = (float*)((char*)d_ws + offU);
        int*      gcur     = (int*)((char*)d_ws + offGcur);
        float*    accum    = (float*)((char*)d_ws + offAccum);
        int*      done     = (int*)((char*)d_ws + offDone);
        int*      chunkOff = (int*)((char*)d_ws + offCOff);
        float*    P1       = (float*)((char*)d_ws + offP1);
        float2*   P2       = (float2*)((char*)d_ws + offP2);

        hipMemsetAsync(gcur, 0, (size_t)nbuck * 4 + 12, stream);

        int epb = (((E + SORT_BLK - 1) / SORT_BLK) + 3) & ~3;
        int gridNode = (N + TPB - 1) / TPB;

        k_sort<<<SORT_BLK, TPB, 0, stream>>>(ei, E, epb, nbuck, gcur, packed);
        k_sort2<<<nbuck, TPB2, 0, stream>>>(packed, gcur, x, dinv, u, chunkOff, nch, N);
        k_agg1<<<nch * G1, TPB, 0, stream>>>(packed, chunkOff, u, P1, nbuck, G1, N);
        k_mid<<<gridNode, TPB, 0, stream>>>(P1, dinv, u, W1, b1, W2, w, nch, N);
        k_agg2<<<nch * G2, TPB, 0, stream>>>(packed, chunkOff, (const float2*)w, P2,
                                             nbuck, G2, N);
        k_out<<<gridNode, TPB, 0, stream>>>((const float2*)P2, dinv, (const float2*)w, b2,
                                            accum, done, out, 1.0f / (float)N, nch, N);
    } else {
        int*   deg   = (int*)d_ws;
        float* t     = (float*)(deg + N);
        float* acc   = t + N;
        float* accum = acc + 2 * N;
        float* dinv  = accum + 2;
        float* u     = dinv + N;
        float2* w    = (float2*)(u + N);
        hipMemsetAsync(d_ws, 0, (size_t)(4 * N + 2) * sizeof(float), stream);
        k_hist<<<gridE, FTPB, 0, stream>>>(ei + E, E, deg);
        k_dinv_u<<<gridN, FTPB, 0, stream>>>(deg, x, dinv, u, N);
        k_scatter1<<<gridE, FTPB, 0, stream>>>(ei, E, u, t);
        k_node_mid_fb<<<gridN, FTPB, 0, stream>>>(dinv, u, t, W1, b1, W2, w, N);
        k_scatter2<<<gridE, FTPB, 0, stream>>>(ei, E, w, acc);
        k_node_out_fb<<<gridN, FTPB, 0, stream>>>(dinv, w, (const float2*)acc, b2, accum, N);
        k_finalize<<<1, 64, 0, stream>>>(accum, out, 1.0f / (float)N);
    }
}